// Round 3
// baseline (347.096 us; speedup 1.0000x reference)
//
#include <hip/hip_runtime.h>
#include <math.h>

// ---------------------------------------------------------------------------
// GCNEncoder: 3 stacked GCNConv layers (symmetric norm, self-loops) + ReLU.
//   - edge dtype auto-detect (int64 vs int32); hist/fill read edges directly.
//   - dst-CSR per call: histogram -> 2-level scan -> fill.
//   - transform1: LDS-tiled fp32 GEMM, global_load_lds staging (X tile 32KB
//     linear + W 8KB chunks), 40KB LDS -> 4 blocks/CU. hs1 = dinv.*(x@W1).
//   - fused agg1+transform2: gather out1 tile (ReLU) into LDS, in-block GEMM
//     with W2 -> hs2 = dinv.*(relu(out1)@W2). out1 never hits HBM.
//   - agg2 fuses W3 via 32-lane shuffle; agg3 produces final output.
// ---------------------------------------------------------------------------

#define FULL_GRID 2048

typedef const __attribute__((address_space(1))) void* gas_ptr;
typedef __attribute__((address_space(3))) void* las_ptr;

__device__ __forceinline__ void gld16(const void* g, void* l) {
  __builtin_amdgcn_global_load_lds((gas_ptr)g, (las_ptr)l, 16, 0, 0);
}

__global__ __launch_bounds__(256) void k_detect(const unsigned int* __restrict__ words,
                                                int* __restrict__ flag) {
  __shared__ int sm[256];
  int cnt = 0;
  #pragma unroll
  for (int j = 0; j < 8; ++j) {
    int idx = (threadIdx.x * 8 + j) * 2 + 1;  // odd words of first 4096 words
    cnt += (words[idx] == 0u) ? 1 : 0;
  }
  sm[threadIdx.x] = cnt;
  __syncthreads();
  for (int off = 128; off > 0; off >>= 1) {
    if (threadIdx.x < off) sm[threadIdx.x] += sm[threadIdx.x + off];
    __syncthreads();
  }
  if (threadIdx.x == 0) flag[0] = (sm[0] > 1024) ? 1 : 0;
}

__global__ __launch_bounds__(256) void k_hist(const void* __restrict__ eraw, int E,
                                              const int* __restrict__ flag,
                                              int* __restrict__ counts) {
  const int is64 = flag[0];
  int i = blockIdx.x * blockDim.x + threadIdx.x;
  const int stride = gridDim.x * blockDim.x;
  if (is64) {
    const long long* e = (const long long*)eraw;
    for (; i < E; i += stride) atomicAdd(&counts[(int)e[(long long)E + i]], 1);
  } else {
    const int* e = (const int*)eraw;
    for (; i < E; i += stride) atomicAdd(&counts[e[E + i]], 1);
  }
}

__global__ __launch_bounds__(1024) void k_scan1(const int* __restrict__ counts,
                                                int* __restrict__ scanned,
                                                int* __restrict__ partials, int n) {
  __shared__ int sm[1024];
  const int i = blockIdx.x * 1024 + threadIdx.x;
  const int v = (i < n) ? counts[i] : 0;
  sm[threadIdx.x] = v;
  __syncthreads();
  for (int off = 1; off < 1024; off <<= 1) {
    int t = sm[threadIdx.x];
    int u = (threadIdx.x >= off) ? sm[threadIdx.x - off] : 0;
    __syncthreads();
    sm[threadIdx.x] = t + u;
    __syncthreads();
  }
  const int inc = sm[threadIdx.x];
  if (i < n) scanned[i] = inc - v;  // exclusive
  if (threadIdx.x == 1023) partials[blockIdx.x] = inc;
}

__global__ __launch_bounds__(1024) void k_scan2(int* __restrict__ partials, int nb) {
  __shared__ int sm[1024];
  const int v = (threadIdx.x < nb) ? partials[threadIdx.x] : 0;
  sm[threadIdx.x] = v;
  __syncthreads();
  for (int off = 1; off < 1024; off <<= 1) {
    int t = sm[threadIdx.x];
    int u = (threadIdx.x >= off) ? sm[threadIdx.x - off] : 0;
    __syncthreads();
    sm[threadIdx.x] = t + u;
    __syncthreads();
  }
  if (threadIdx.x < nb) partials[threadIdx.x] = sm[threadIdx.x] - v;  // exclusive
}

__global__ __launch_bounds__(256) void k_scan3(const int* __restrict__ scanned,
                                               const int* __restrict__ partials,
                                               const int* __restrict__ counts,
                                               int* __restrict__ offsets,
                                               int* __restrict__ cursor,
                                               float* __restrict__ dinv, int n) {
  int i = blockIdx.x * blockDim.x + threadIdx.x;
  const int stride = gridDim.x * blockDim.x;
  for (; i < n; i += stride) {
    const int o = scanned[i] + partials[i >> 10];
    offsets[i] = o;
    cursor[i] = o;
    dinv[i] = rsqrtf((float)counts[i] + 1.0f);  // +1 self-loop
  }
}

__global__ __launch_bounds__(256) void k_fill(const void* __restrict__ eraw, int E,
                                              const int* __restrict__ flag,
                                              int* __restrict__ cursor,
                                              int* __restrict__ elist) {
  const int is64 = flag[0];
  int i = blockIdx.x * blockDim.x + threadIdx.x;
  const int stride = gridDim.x * blockDim.x;
  if (is64) {
    const long long* e = (const long long*)eraw;
    for (; i < E; i += stride) {
      const int s = (int)e[i];
      const int d = (int)e[(long long)E + i];
      elist[atomicAdd(&cursor[d], 1)] = s;
    }
  } else {
    const int* e = (const int*)eraw;
    for (; i < E; i += stride) {
      const int s = e[i];
      const int d = e[E + i];
      elist[atomicAdd(&cursor[d], 1)] = s;
    }
  }
}

// hs = dinv .* (X @ W).  TILE_M=64, 256 thr, 4x4 thread tile.
// Xs linear (no pad) + Ws KC-chunks, both staged via global_load_lds.
template <int F_IN, int F_OUT, int TILE_M, int KC>
__global__ __launch_bounds__(256) void k_transform(const float* __restrict__ X,
                                                   const float* __restrict__ W,
                                                   const float* __restrict__ dinv,
                                                   float* __restrict__ H, int n) {
  constexpr int COLT = F_OUT / 4;    // 16
  constexpr int ROWT = 256 / COLT;   // 16
  constexpr int TM = TILE_M / ROWT;  // 4
  constexpr int NKC = F_IN / KC;
  static_assert(TM * ROWT == TILE_M && COLT * 4 == F_OUT, "tiling");
  static_assert((TILE_M * F_IN * 4) % 1024 == 0 && (KC * F_OUT * 4) % 1024 == 0, "segs");

  __shared__ __align__(16) float Xs[TILE_M * F_IN];
  __shared__ __align__(16) float Ws[KC * F_OUT];

  const int tid = threadIdx.x;
  const int lane = tid & 63;
  const int wid = tid >> 6;
  const long long base = (long long)blockIdx.x * TILE_M;

  if (base + TILE_M <= n) {  // full tile: async staged, contiguous rows
    constexpr int SEGS = TILE_M * F_IN * 4 / 1024;  // 1KB segments
    constexpr int PW = SEGS / 4;
    const float* gbase = X + base * F_IN;
    #pragma unroll
    for (int j = 0; j < PW; ++j) {
      const int seg = wid * PW + j;
      gld16(gbase + seg * 256 + lane * 4, &Xs[seg * 256]);
    }
  } else {  // tail tile: guarded vector staging, zero fill
    const float4* __restrict__ X4 = (const float4*)X;
    for (int g = tid; g < TILE_M * F_IN / 4; g += 256) {
      const int row = g / (F_IN / 4), c4 = g % (F_IN / 4);
      float4 v = make_float4(0.f, 0.f, 0.f, 0.f);
      if (base + row < n) v = X4[(base + row) * (F_IN / 4) + c4];
      ((float4*)Xs)[g] = v;
    }
  }

  const int ct = tid % COLT;
  const int rt = tid / COLT;

  float4 acc[TM];
  #pragma unroll
  for (int r = 0; r < TM; ++r) acc[r] = make_float4(0.f, 0.f, 0.f, 0.f);

  const float4* Xs4 = (const float4*)Xs;
  const float4* Ws4 = (const float4*)Ws;

  for (int kc = 0; kc < NKC; ++kc) {
    __syncthreads();  // prev Ws consumed (and vmcnt drained for staging)
    {
      constexpr int WSEG = KC * F_OUT * 4 / 1024;
      constexpr int WPW = WSEG / 4;
      const float* wb = W + kc * KC * F_OUT;
      #pragma unroll
      for (int j = 0; j < WPW; ++j) {
        const int seg = wid * WPW + j;
        gld16(wb + seg * 256 + lane * 4, &Ws[seg * 256]);
      }
    }
    __syncthreads();
    #pragma unroll
    for (int k4 = 0; k4 < KC / 4; ++k4) {
      float4 wv0 = Ws4[(k4 * 4 + 0) * COLT + ct];
      float4 wv1 = Ws4[(k4 * 4 + 1) * COLT + ct];
      float4 wv2 = Ws4[(k4 * 4 + 2) * COLT + ct];
      float4 wv3 = Ws4[(k4 * 4 + 3) * COLT + ct];
      #pragma unroll
      for (int r = 0; r < TM; ++r) {
        const float4 xv = Xs4[(rt + r * ROWT) * (F_IN / 4) + kc * (KC / 4) + k4];
        acc[r].x = fmaf(xv.x, wv0.x, acc[r].x);
        acc[r].y = fmaf(xv.x, wv0.y, acc[r].y);
        acc[r].z = fmaf(xv.x, wv0.z, acc[r].z);
        acc[r].w = fmaf(xv.x, wv0.w, acc[r].w);
        acc[r].x = fmaf(xv.y, wv1.x, acc[r].x);
        acc[r].y = fmaf(xv.y, wv1.y, acc[r].y);
        acc[r].z = fmaf(xv.y, wv1.z, acc[r].z);
        acc[r].w = fmaf(xv.y, wv1.w, acc[r].w);
        acc[r].x = fmaf(xv.z, wv2.x, acc[r].x);
        acc[r].y = fmaf(xv.z, wv2.y, acc[r].y);
        acc[r].z = fmaf(xv.z, wv2.z, acc[r].z);
        acc[r].w = fmaf(xv.z, wv2.w, acc[r].w);
        acc[r].x = fmaf(xv.w, wv3.x, acc[r].x);
        acc[r].y = fmaf(xv.w, wv3.y, acc[r].y);
        acc[r].z = fmaf(xv.w, wv3.z, acc[r].z);
        acc[r].w = fmaf(xv.w, wv3.w, acc[r].w);
      }
    }
  }

  #pragma unroll
  for (int r = 0; r < TM; ++r) {
    const long long row = base + rt + r * ROWT;
    if (row < n) {
      const float di = dinv[row];
      float4 v = acc[r];
      v.x *= di; v.y *= di; v.z *= di; v.w *= di;
      *(float4*)&H[row * F_OUT + ct * 4] = v;
    }
  }
}

// Fused: out1 = relu(b1 + dinv.*(gather hs1)) ; hs2 = dinv .* (out1 @ W2)
// Block = 64 dst nodes. Phase 1: wave-per-node gather (lane=feature, F=64)
// into LDS Os[64][68]. Phase 2: in-block GEMM 64x64 @ 64x32.
__global__ __launch_bounds__(256) void k_agg1_t2(const float* __restrict__ HS1,
                                                 const float* __restrict__ dinv,
                                                 const int* __restrict__ offsets,
                                                 const int* __restrict__ counts,
                                                 const int* __restrict__ elist,
                                                 const float* __restrict__ b1,
                                                 const float* __restrict__ W2,
                                                 float* __restrict__ HS2, int n) {
  __shared__ __align__(16) float Os[64 * 68];
  __shared__ __align__(16) float W2s[64 * 32];
  __shared__ float Ds[64];

  const int tid = threadIdx.x;
  const int lane = tid & 63;
  const int wid = tid >> 6;
  const long long base = (long long)blockIdx.x * 64;

  for (int i = tid; i < 64 * 32 / 4; i += 256)
    ((float4*)W2s)[i] = ((const float4*)W2)[i];

  const float bf = b1[lane];
  for (int t = 0; t < 16; ++t) {
    const int rl = wid * 16 + t;  // row-local
    const long long d = base + rl;
    float r = 0.f;
    if (d < n) {
      const float di = dinv[d];
      float acc = HS1[d * 64 + lane];  // self-loop (dinv[d]-scaled already)
      const int start = offsets[d];
      const int cnt = counts[d];
      int j = 0;
      for (; j + 4 <= cnt; j += 4) {
        const int s0 = elist[start + j + 0];
        const int s1 = elist[start + j + 1];
        const int s2 = elist[start + j + 2];
        const int s3 = elist[start + j + 3];
        const float v0 = HS1[(long long)s0 * 64 + lane];
        const float v1 = HS1[(long long)s1 * 64 + lane];
        const float v2 = HS1[(long long)s2 * 64 + lane];
        const float v3 = HS1[(long long)s3 * 64 + lane];
        acc += (v0 + v1) + (v2 + v3);
      }
      for (; j < cnt; ++j) acc += HS1[(long long)elist[start + j] * 64 + lane];
      r = fmaxf(fmaf(di, acc, bf), 0.f);
      if (lane == 0) Ds[rl] = di;
    }
    Os[rl * 68 + lane] = r;
  }
  __syncthreads();

  // GEMM: rows {rt, rt+32}, cols ct*4..ct*4+3
  const int ct = tid & 7;
  const int rt = tid >> 3;
  const float4* Os4 = (const float4*)Os;
  const float4* W2s4 = (const float4*)W2s;
  float4 a0 = make_float4(0.f, 0.f, 0.f, 0.f);
  float4 a1 = make_float4(0.f, 0.f, 0.f, 0.f);
  #pragma unroll
  for (int k4 = 0; k4 < 16; ++k4) {
    float4 w0 = W2s4[(k4 * 4 + 0) * 8 + ct];
    float4 w1 = W2s4[(k4 * 4 + 1) * 8 + ct];
    float4 w2 = W2s4[(k4 * 4 + 2) * 8 + ct];
    float4 w3 = W2s4[(k4 * 4 + 3) * 8 + ct];
    const float4 x0 = Os4[rt * 17 + k4];
    const float4 x1 = Os4[(rt + 32) * 17 + k4];
    a0.x = fmaf(x0.x, w0.x, a0.x); a0.y = fmaf(x0.x, w0.y, a0.y);
    a0.z = fmaf(x0.x, w0.z, a0.z); a0.w = fmaf(x0.x, w0.w, a0.w);
    a0.x = fmaf(x0.y, w1.x, a0.x); a0.y = fmaf(x0.y, w1.y, a0.y);
    a0.z = fmaf(x0.y, w1.z, a0.z); a0.w = fmaf(x0.y, w1.w, a0.w);
    a0.x = fmaf(x0.z, w2.x, a0.x); a0.y = fmaf(x0.z, w2.y, a0.y);
    a0.z = fmaf(x0.z, w2.z, a0.z); a0.w = fmaf(x0.z, w2.w, a0.w);
    a0.x = fmaf(x0.w, w3.x, a0.x); a0.y = fmaf(x0.w, w3.y, a0.y);
    a0.z = fmaf(x0.w, w3.z, a0.z); a0.w = fmaf(x0.w, w3.w, a0.w);
    a1.x = fmaf(x1.x, w0.x, a1.x); a1.y = fmaf(x1.x, w0.y, a1.y);
    a1.z = fmaf(x1.x, w0.z, a1.z); a1.w = fmaf(x1.x, w0.w, a1.w);
    a1.x = fmaf(x1.y, w1.x, a1.x); a1.y = fmaf(x1.y, w1.y, a1.y);
    a1.z = fmaf(x1.y, w1.z, a1.z); a1.w = fmaf(x1.y, w1.w, a1.w);
    a1.x = fmaf(x1.z, w2.x, a1.x); a1.y = fmaf(x1.z, w2.y, a1.y);
    a1.z = fmaf(x1.z, w2.z, a1.z); a1.w = fmaf(x1.z, w2.w, a1.w);
    a1.x = fmaf(x1.w, w3.x, a1.x); a1.y = fmaf(x1.w, w3.y, a1.y);
    a1.z = fmaf(x1.w, w3.z, a1.z); a1.w = fmaf(x1.w, w3.w, a1.w);
  }
  const long long r0 = base + rt;
  const long long r1 = base + rt + 32;
  if (r0 < n) {
    const float di = Ds[rt];
    a0.x *= di; a0.y *= di; a0.z *= di; a0.w *= di;
    *(float4*)&HS2[r0 * 32 + ct * 4] = a0;
  }
  if (r1 < n) {
    const float di = Ds[rt + 32];
    a1.x *= di; a1.y *= di; a1.z *= di; a1.w *= di;
    *(float4*)&HS2[r1 * 32 + ct * 4] = a1;
  }
}

// out[d][f] = relu(b[f] + dinv[d]*(hs[d][f] + sum_s hs[s][f]))
// FUSE_W3: additionally hs3 = dinv .* (relu(out2) @ W3)  (F_OUT=2).
template <int F, bool RELU_OUT, bool FUSE_W3>
__global__ __launch_bounds__(256) void k_aggregate(const float* __restrict__ HS,
                                                   const float* __restrict__ dinv,
                                                   const int* __restrict__ offsets,
                                                   const int* __restrict__ counts,
                                                   const int* __restrict__ elist,
                                                   const float* __restrict__ bias,
                                                   const float* __restrict__ W3,
                                                   float* __restrict__ out, int n) {
  const int f = threadIdx.x % F;
  const int grp = threadIdx.x / F;
  constexpr int GRPS = 256 / F;
  const float bf = bias[f];
  float w30 = 0.f, w31 = 0.f;
  if (FUSE_W3) { w30 = W3[f * 2 + 0]; w31 = W3[f * 2 + 1]; }

  for (long long d = (long long)blockIdx.x * GRPS + grp; d < n;
       d += (long long)gridDim.x * GRPS) {
    const float di = dinv[d];
    float acc = HS[d * F + f];  // self-loop (already dinv[d]-scaled)
    const int start = offsets[d];
    const int cnt = counts[d];
    int j = 0;
    for (; j + 4 <= cnt; j += 4) {
      const int s0 = elist[start + j + 0];
      const int s1 = elist[start + j + 1];
      const int s2 = elist[start + j + 2];
      const int s3 = elist[start + j + 3];
      const float v0 = HS[(long long)s0 * F + f];
      const float v1 = HS[(long long)s1 * F + f];
      const float v2 = HS[(long long)s2 * F + f];
      const float v3 = HS[(long long)s3 * F + f];
      acc += (v0 + v1) + (v2 + v3);
    }
    for (; j < cnt; ++j) acc += HS[(long long)elist[start + j] * F + f];

    float r = fmaf(di, acc, bf);
    if (RELU_OUT) r = fmaxf(r, 0.f);
    if (!FUSE_W3) {
      out[d * F + f] = r;
    } else {
      float t0 = r * w30, t1 = r * w31;
      #pragma unroll
      for (int m = 1; m < 32; m <<= 1) {
        t0 += __shfl_xor(t0, m, 64);
        t1 += __shfl_xor(t1, m, 64);
      }
      if (f == 0) {
        out[d * 2 + 0] = di * t0;
        out[d * 2 + 1] = di * t1;
      }
    }
  }
}

extern "C" void kernel_launch(void* const* d_in, const int* in_sizes, int n_in,
                              void* d_out, int out_size, void* d_ws, size_t ws_size,
                              hipStream_t stream) {
  const float* x = (const float*)d_in[0];
  const void* eraw = d_in[1];
  const float* W1 = (const float*)d_in[2];
  const float* b1 = (const float*)d_in[3];
  const float* W2 = (const float*)d_in[4];
  const float* b2 = (const float*)d_in[5];
  const float* W3 = (const float*)d_in[6];
  const float* b3 = (const float*)d_in[7];
  float* out = (float*)d_out;

  const int N = in_sizes[0] / 128;  // 100000
  const int E = in_sizes[1] / 2;    // 600000

  char* ws = (char*)d_ws;
  size_t off = 0;
  auto alloc = [&](size_t bytes) -> char* {
    char* p = ws + off;
    off = (off + bytes + 255) & ~(size_t)255;
    return p;
  };
  int*   flag     = (int*)alloc(256);
  int*   counts   = (int*)alloc((size_t)N * 4);
  int*   scanned  = (int*)alloc((size_t)N * 4);
  int*   partials = (int*)alloc(1024 * 4);
  int*   offsets  = (int*)alloc((size_t)N * 4);
  int*   cursor   = (int*)alloc((size_t)N * 4);
  int*   elist    = (int*)alloc((size_t)E * 4);
  float* dinv     = (float*)alloc((size_t)N * 4);
  float* hbuf     = (float*)alloc((size_t)N * 64 * 4);  // hs1 [N,64]; later hs3 [N,2]
  float* obuf     = (float*)alloc((size_t)N * 32 * 4);  // hs2 [N,32]
  (void)ws_size; (void)n_in; (void)out_size;

  // ---- CSR build ----
  hipMemsetAsync(counts, 0, (size_t)N * 4, stream);
  k_detect<<<1, 256, 0, stream>>>((const unsigned int*)eraw, flag);
  k_hist<<<FULL_GRID, 256, 0, stream>>>(eraw, E, flag, counts);
  const int NB = (N + 1023) >> 10;
  k_scan1<<<NB, 1024, 0, stream>>>(counts, scanned, partials, N);
  k_scan2<<<1, 1024, 0, stream>>>(partials, NB);
  k_scan3<<<(N + 255) / 256, 256, 0, stream>>>(scanned, partials, counts, offsets,
                                               cursor, dinv, N);
  k_fill<<<FULL_GRID, 256, 0, stream>>>(eraw, E, flag, cursor, elist);

  // ---- layer 1 transform: hs1 = dinv.*(x@W1) ----
  k_transform<128, 64, 64, 32><<<(N + 63) / 64, 256, 0, stream>>>(x, W1, dinv, hbuf, N);
  // ---- fused layer-1 aggregate + layer-2 transform ----
  k_agg1_t2<<<(N + 63) / 64, 256, 0, stream>>>(hbuf, dinv, offsets, counts, elist,
                                               b1, W2, obuf, N);
  // ---- layer-2 aggregate + ReLU + fused W3 -> hs3 ----
  k_aggregate<32, true, true><<<(N + 7) / 8, 256, 0, stream>>>(
      obuf, dinv, offsets, counts, elist, b2, W3, hbuf, N);
  // ---- layer-3 aggregate + ReLU -> out ----
  k_aggregate<2, true, false><<<(N + 127) / 128, 256, 0, stream>>>(
      hbuf, dinv, offsets, counts, elist, b3, nullptr, out, N);
}

// Round 4
// 206.992 us; speedup vs baseline: 1.6769x; 1.6769x over previous
//
#include <hip/hip_runtime.h>
#include <math.h>

// ---------------------------------------------------------------------------
// GCNEncoder: 3 stacked GCNConv layers (symmetric norm, self-loops) + ReLU.
//   R4: revert R3's agg1+t2 fusion (VGPR 176 -> 10% occupancy disaster).
//   - separate low-VGPR aggregates (8-wide predicated gather batches)
//   - global_load_lds-staged transforms (40KB LDS -> 4 blocks/CU)
//   - layer-3 transform fused into layer-2 aggregate via shuffle reduce
// ---------------------------------------------------------------------------

#define FULL_GRID 2048

typedef const __attribute__((address_space(1))) void* gas_ptr;
typedef __attribute__((address_space(3))) void* las_ptr;

__device__ __forceinline__ void gld16(const void* g, void* l) {
  __builtin_amdgcn_global_load_lds((gas_ptr)g, (las_ptr)l, 16, 0, 0);
}

__global__ __launch_bounds__(256) void k_detect(const unsigned int* __restrict__ words,
                                                int* __restrict__ flag) {
  __shared__ int sm[256];
  int cnt = 0;
  #pragma unroll
  for (int j = 0; j < 8; ++j) {
    int idx = (threadIdx.x * 8 + j) * 2 + 1;  // odd words of first 4096 words
    cnt += (words[idx] == 0u) ? 1 : 0;
  }
  sm[threadIdx.x] = cnt;
  __syncthreads();
  for (int off = 128; off > 0; off >>= 1) {
    if (threadIdx.x < off) sm[threadIdx.x] += sm[threadIdx.x + off];
    __syncthreads();
  }
  if (threadIdx.x == 0) flag[0] = (sm[0] > 1024) ? 1 : 0;
}

__global__ __launch_bounds__(256) void k_hist(const void* __restrict__ eraw, int E,
                                              const int* __restrict__ flag,
                                              int* __restrict__ counts) {
  const int is64 = flag[0];
  int i = blockIdx.x * blockDim.x + threadIdx.x;
  const int stride = gridDim.x * blockDim.x;
  if (is64) {
    const long long* e = (const long long*)eraw;
    for (; i < E; i += stride) atomicAdd(&counts[(int)e[(long long)E + i]], 1);
  } else {
    const int* e = (const int*)eraw;
    for (; i < E; i += stride) atomicAdd(&counts[e[E + i]], 1);
  }
}

__global__ __launch_bounds__(1024) void k_scan1(const int* __restrict__ counts,
                                                int* __restrict__ scanned,
                                                int* __restrict__ partials, int n) {
  __shared__ int sm[1024];
  const int i = blockIdx.x * 1024 + threadIdx.x;
  const int v = (i < n) ? counts[i] : 0;
  sm[threadIdx.x] = v;
  __syncthreads();
  for (int off = 1; off < 1024; off <<= 1) {
    int t = sm[threadIdx.x];
    int u = (threadIdx.x >= off) ? sm[threadIdx.x - off] : 0;
    __syncthreads();
    sm[threadIdx.x] = t + u;
    __syncthreads();
  }
  const int inc = sm[threadIdx.x];
  if (i < n) scanned[i] = inc - v;  // exclusive
  if (threadIdx.x == 1023) partials[blockIdx.x] = inc;
}

__global__ __launch_bounds__(1024) void k_scan2(int* __restrict__ partials, int nb) {
  __shared__ int sm[1024];
  const int v = (threadIdx.x < nb) ? partials[threadIdx.x] : 0;
  sm[threadIdx.x] = v;
  __syncthreads();
  for (int off = 1; off < 1024; off <<= 1) {
    int t = sm[threadIdx.x];
    int u = (threadIdx.x >= off) ? sm[threadIdx.x - off] : 0;
    __syncthreads();
    sm[threadIdx.x] = t + u;
    __syncthreads();
  }
  if (threadIdx.x < nb) partials[threadIdx.x] = sm[threadIdx.x] - v;  // exclusive
}

__global__ __launch_bounds__(256) void k_scan3(const int* __restrict__ scanned,
                                               const int* __restrict__ partials,
                                               const int* __restrict__ counts,
                                               int* __restrict__ offsets,
                                               int* __restrict__ cursor,
                                               float* __restrict__ dinv, int n) {
  int i = blockIdx.x * blockDim.x + threadIdx.x;
  const int stride = gridDim.x * blockDim.x;
  for (; i < n; i += stride) {
    const int o = scanned[i] + partials[i >> 10];
    offsets[i] = o;
    cursor[i] = o;
    dinv[i] = rsqrtf((float)counts[i] + 1.0f);  // +1 self-loop
  }
}

__global__ __launch_bounds__(256) void k_fill(const void* __restrict__ eraw, int E,
                                              const int* __restrict__ flag,
                                              int* __restrict__ cursor,
                                              int* __restrict__ elist) {
  const int is64 = flag[0];
  int i = blockIdx.x * blockDim.x + threadIdx.x;
  const int stride = gridDim.x * blockDim.x;
  if (is64) {
    const long long* e = (const long long*)eraw;
    for (; i < E; i += stride) {
      const int s = (int)e[i];
      const int d = (int)e[(long long)E + i];
      elist[atomicAdd(&cursor[d], 1)] = s;
    }
  } else {
    const int* e = (const int*)eraw;
    for (; i < E; i += stride) {
      const int s = e[i];
      const int d = e[E + i];
      elist[atomicAdd(&cursor[d], 1)] = s;
    }
  }
}

// hs = dinv .* (X @ W).  256 thr, 4x4 thread tile.
// Xs linear (no pad) + Ws KC-chunks, both staged via global_load_lds.
template <int F_IN, int F_OUT, int TILE_M, int KC>
__global__ __launch_bounds__(256) void k_transform(const float* __restrict__ X,
                                                   const float* __restrict__ W,
                                                   const float* __restrict__ dinv,
                                                   float* __restrict__ H, int n) {
  constexpr int COLT = F_OUT / 4;
  constexpr int ROWT = 256 / COLT;
  constexpr int TM = TILE_M / ROWT;
  constexpr int NKC = F_IN / KC;
  static_assert(TM * ROWT == TILE_M && COLT * 4 == F_OUT, "tiling");
  static_assert((TILE_M * F_IN * 4) % 1024 == 0 && (KC * F_OUT * 4) % 1024 == 0, "segs");

  __shared__ __align__(16) float Xs[TILE_M * F_IN];
  __shared__ __align__(16) float Ws[KC * F_OUT];

  const int tid = threadIdx.x;
  const int lane = tid & 63;
  const int wid = tid >> 6;
  const long long base = (long long)blockIdx.x * TILE_M;

  if (base + TILE_M <= n) {  // full tile: async staged, contiguous rows
    constexpr int SEGS = TILE_M * F_IN * 4 / 1024;  // 1KB segments
    constexpr int PW = SEGS / 4;
    const float* gbase = X + base * F_IN;
    #pragma unroll
    for (int j = 0; j < PW; ++j) {
      const int seg = wid * PW + j;
      gld16(gbase + seg * 256 + lane * 4, &Xs[seg * 256]);
    }
  } else {  // tail tile: guarded vector staging, zero fill
    const float4* __restrict__ X4 = (const float4*)X;
    for (int g = tid; g < TILE_M * F_IN / 4; g += 256) {
      const int row = g / (F_IN / 4), c4 = g % (F_IN / 4);
      float4 v = make_float4(0.f, 0.f, 0.f, 0.f);
      if (base + row < n) v = X4[(base + row) * (F_IN / 4) + c4];
      ((float4*)Xs)[g] = v;
    }
  }

  const int ct = tid % COLT;
  const int rt = tid / COLT;

  float4 acc[TM];
  #pragma unroll
  for (int r = 0; r < TM; ++r) acc[r] = make_float4(0.f, 0.f, 0.f, 0.f);

  const float4* Xs4 = (const float4*)Xs;
  const float4* Ws4 = (const float4*)Ws;

  for (int kc = 0; kc < NKC; ++kc) {
    __syncthreads();  // prev Ws consumed / staging drained
    {
      constexpr int WSEG = KC * F_OUT * 4 / 1024;
      constexpr int WPW = WSEG / 4;
      const float* wb = W + kc * KC * F_OUT;
      #pragma unroll
      for (int j = 0; j < WPW; ++j) {
        const int seg = wid * WPW + j;
        gld16(wb + seg * 256 + lane * 4, &Ws[seg * 256]);
      }
    }
    __syncthreads();
    #pragma unroll
    for (int k4 = 0; k4 < KC / 4; ++k4) {
      float4 wv0 = Ws4[(k4 * 4 + 0) * COLT + ct];
      float4 wv1 = Ws4[(k4 * 4 + 1) * COLT + ct];
      float4 wv2 = Ws4[(k4 * 4 + 2) * COLT + ct];
      float4 wv3 = Ws4[(k4 * 4 + 3) * COLT + ct];
      #pragma unroll
      for (int r = 0; r < TM; ++r) {
        const float4 xv = Xs4[(rt + r * ROWT) * (F_IN / 4) + kc * (KC / 4) + k4];
        acc[r].x = fmaf(xv.x, wv0.x, acc[r].x);
        acc[r].y = fmaf(xv.x, wv0.y, acc[r].y);
        acc[r].z = fmaf(xv.x, wv0.z, acc[r].z);
        acc[r].w = fmaf(xv.x, wv0.w, acc[r].w);
        acc[r].x = fmaf(xv.y, wv1.x, acc[r].x);
        acc[r].y = fmaf(xv.y, wv1.y, acc[r].y);
        acc[r].z = fmaf(xv.y, wv1.z, acc[r].z);
        acc[r].w = fmaf(xv.y, wv1.w, acc[r].w);
        acc[r].x = fmaf(xv.z, wv2.x, acc[r].x);
        acc[r].y = fmaf(xv.z, wv2.y, acc[r].y);
        acc[r].z = fmaf(xv.z, wv2.z, acc[r].z);
        acc[r].w = fmaf(xv.z, wv2.w, acc[r].w);
        acc[r].x = fmaf(xv.w, wv3.x, acc[r].x);
        acc[r].y = fmaf(xv.w, wv3.y, acc[r].y);
        acc[r].z = fmaf(xv.w, wv3.z, acc[r].z);
        acc[r].w = fmaf(xv.w, wv3.w, acc[r].w);
      }
    }
  }

  #pragma unroll
  for (int r = 0; r < TM; ++r) {
    const long long row = base + rt + r * ROWT;
    if (row < n) {
      const float di = dinv[row];
      float4 v = acc[r];
      v.x *= di; v.y *= di; v.z *= di; v.w *= di;
      *(float4*)&H[row * F_OUT + ct * 4] = v;
    }
  }
}

// out[d][f] = relu?(b[f] + dinv[d]*(hs[d][f] + sum_s hs[s][f]))
// 8-wide predicated gather batches: 8 independent loads in flight per group.
// FUSE_W3: additionally hs3 = dinv .* (relu(out2) @ W3)  (F_OUT=2).
template <int F, bool RELU_OUT, bool FUSE_W3>
__global__ __launch_bounds__(256) void k_aggregate(const float* __restrict__ HS,
                                                   const float* __restrict__ dinv,
                                                   const int* __restrict__ offsets,
                                                   const int* __restrict__ counts,
                                                   const int* __restrict__ elist,
                                                   const float* __restrict__ bias,
                                                   const float* __restrict__ W3,
                                                   float* __restrict__ out, int n) {
  const int f = threadIdx.x % F;
  const int grp = threadIdx.x / F;
  constexpr int GRPS = 256 / F;
  const float bf = bias[f];
  float w30 = 0.f, w31 = 0.f;
  if (FUSE_W3) { w30 = W3[f * 2 + 0]; w31 = W3[f * 2 + 1]; }

  for (long long d = (long long)blockIdx.x * GRPS + grp; d < n;
       d += (long long)gridDim.x * GRPS) {
    const float di = dinv[d];
    float acc = HS[d * F + f];  // self-loop (already dinv[d]-scaled)
    const int start = offsets[d];
    const int cnt = counts[d];
    for (int j = 0; j < cnt; j += 8) {
      int idx[8];
      float v[8];
      #pragma unroll
      for (int t = 0; t < 8; ++t) {
        const int jj = (j + t < cnt) ? (j + t) : j;  // clamp to a valid slot
        idx[t] = elist[start + jj];
      }
      #pragma unroll
      for (int t = 0; t < 8; ++t) v[t] = HS[(long long)idx[t] * F + f];
      #pragma unroll
      for (int t = 0; t < 8; ++t) acc += (j + t < cnt) ? v[t] : 0.f;
    }

    float r = fmaf(di, acc, bf);
    if (RELU_OUT) r = fmaxf(r, 0.f);
    if (!FUSE_W3) {
      out[d * F + f] = r;
    } else {
      float t0 = r * w30, t1 = r * w31;
      #pragma unroll
      for (int m = 1; m < 32; m <<= 1) {
        t0 += __shfl_xor(t0, m, 64);
        t1 += __shfl_xor(t1, m, 64);
      }
      if (f == 0) {
        out[d * 2 + 0] = di * t0;
        out[d * 2 + 1] = di * t1;
      }
    }
  }
}

extern "C" void kernel_launch(void* const* d_in, const int* in_sizes, int n_in,
                              void* d_out, int out_size, void* d_ws, size_t ws_size,
                              hipStream_t stream) {
  const float* x = (const float*)d_in[0];
  const void* eraw = d_in[1];
  const float* W1 = (const float*)d_in[2];
  const float* b1 = (const float*)d_in[3];
  const float* W2 = (const float*)d_in[4];
  const float* b2 = (const float*)d_in[5];
  const float* W3 = (const float*)d_in[6];
  const float* b3 = (const float*)d_in[7];
  float* out = (float*)d_out;

  const int N = in_sizes[0] / 128;  // 100000
  const int E = in_sizes[1] / 2;    // 600000

  char* ws = (char*)d_ws;
  size_t off = 0;
  auto alloc = [&](size_t bytes) -> char* {
    char* p = ws + off;
    off = (off + bytes + 255) & ~(size_t)255;
    return p;
  };
  int*   flag     = (int*)alloc(256);
  int*   counts   = (int*)alloc((size_t)N * 4);
  int*   scanned  = (int*)alloc((size_t)N * 4);
  int*   partials = (int*)alloc(1024 * 4);
  int*   offsets  = (int*)alloc((size_t)N * 4);
  int*   cursor   = (int*)alloc((size_t)N * 4);
  int*   elist    = (int*)alloc((size_t)E * 4);
  float* dinv     = (float*)alloc((size_t)N * 4);
  float* hbuf     = (float*)alloc((size_t)N * 64 * 4);  // hs1 [N,64]; later hs3 [N,2]
  float* obuf     = (float*)alloc((size_t)N * 64 * 4);  // out1 [N,64]
  float* h2buf    = (float*)alloc((size_t)N * 32 * 4);  // hs2 [N,32]
  (void)ws_size; (void)n_in; (void)out_size;

  // ---- CSR build ----
  hipMemsetAsync(counts, 0, (size_t)N * 4, stream);
  k_detect<<<1, 256, 0, stream>>>((const unsigned int*)eraw, flag);
  k_hist<<<FULL_GRID, 256, 0, stream>>>(eraw, E, flag, counts);
  const int NB = (N + 1023) >> 10;
  k_scan1<<<NB, 1024, 0, stream>>>(counts, scanned, partials, N);
  k_scan2<<<1, 1024, 0, stream>>>(partials, NB);
  k_scan3<<<(N + 255) / 256, 256, 0, stream>>>(scanned, partials, counts, offsets,
                                               cursor, dinv, N);
  k_fill<<<FULL_GRID, 256, 0, stream>>>(eraw, E, flag, cursor, elist);

  // ---- layer 1: hs1 = dinv.*(x@W1); out1 = relu(agg(hs1)) ----
  k_transform<128, 64, 64, 32><<<(N + 63) / 64, 256, 0, stream>>>(x, W1, dinv, hbuf, N);
  k_aggregate<64, true, false><<<(N + 3) / 4, 256, 0, stream>>>(
      hbuf, dinv, offsets, counts, elist, b1, nullptr, obuf, N);

  // ---- layer 2: hs2 = dinv.*(out1@W2); agg + ReLU + fused W3 -> hs3 ----
  k_transform<64, 32, 128, 64><<<(N + 127) / 128, 256, 0, stream>>>(obuf, W2, dinv,
                                                                    h2buf, N);
  k_aggregate<32, true, true><<<(N + 7) / 8, 256, 0, stream>>>(
      h2buf, dinv, offsets, counts, elist, b2, W3, hbuf, N);

  // ---- layer 3: agg hs3 + ReLU -> out ----
  k_aggregate<2, true, false><<<(N + 127) / 128, 256, 0, stream>>>(
      hbuf, dinv, offsets, counts, elist, b3, nullptr, out, N);
}

// Round 5
// 201.972 us; speedup vs baseline: 1.7185x; 1.0249x over previous
//
#include <hip/hip_runtime.h>
#include <math.h>

// ---------------------------------------------------------------------------
// GCNEncoder: 3 stacked GCNConv layers (symmetric norm, self-loops) + ReLU.
//   R5: (a) custom k_zero replaces hipMemsetAsync (fillBufferAligned was
//       39.6us/replay); (b) XOR-swizzled X staging (pre-swizzled global src +
//       swizzled LDS read, m173 pattern) kills the 3.2M LDS bank conflicts;
//       (c) W double-buffered, 1 barrier/chunk. LDS = 40KB -> 4 blocks/CU.
//   Structure otherwise = R4: low-VGPR aggregates (8-wide batches), fused W3.
// ---------------------------------------------------------------------------

#define FULL_GRID 2048

typedef const __attribute__((address_space(1))) void* gas_ptr;
typedef __attribute__((address_space(3))) void* las_ptr;

__device__ __forceinline__ void gld16(const void* g, void* l) {
  __builtin_amdgcn_global_load_lds((gas_ptr)g, (las_ptr)l, 16, 0, 0);
}

__global__ __launch_bounds__(256) void k_zero(int* __restrict__ p, int n4) {
  int i = blockIdx.x * blockDim.x + threadIdx.x;
  const int stride = gridDim.x * blockDim.x;
  int4* p4 = (int4*)p;
  for (; i < n4; i += stride) p4[i] = make_int4(0, 0, 0, 0);
}

__global__ __launch_bounds__(256) void k_detect(const unsigned int* __restrict__ words,
                                                int* __restrict__ flag) {
  __shared__ int sm[256];
  int cnt = 0;
  #pragma unroll
  for (int j = 0; j < 8; ++j) {
    int idx = (threadIdx.x * 8 + j) * 2 + 1;  // odd words of first 4096 words
    cnt += (words[idx] == 0u) ? 1 : 0;
  }
  sm[threadIdx.x] = cnt;
  __syncthreads();
  for (int off = 128; off > 0; off >>= 1) {
    if (threadIdx.x < off) sm[threadIdx.x] += sm[threadIdx.x + off];
    __syncthreads();
  }
  if (threadIdx.x == 0) flag[0] = (sm[0] > 1024) ? 1 : 0;
}

__global__ __launch_bounds__(256) void k_hist(const void* __restrict__ eraw, int E,
                                              const int* __restrict__ flag,
                                              int* __restrict__ counts) {
  const int is64 = flag[0];
  int i = blockIdx.x * blockDim.x + threadIdx.x;
  const int stride = gridDim.x * blockDim.x;
  if (is64) {
    const long long* e = (const long long*)eraw;
    for (; i < E; i += stride) atomicAdd(&counts[(int)e[(long long)E + i]], 1);
  } else {
    const int* e = (const int*)eraw;
    for (; i < E; i += stride) atomicAdd(&counts[e[E + i]], 1);
  }
}

__global__ __launch_bounds__(1024) void k_scan1(const int* __restrict__ counts,
                                                int* __restrict__ scanned,
                                                int* __restrict__ partials, int n) {
  __shared__ int sm[1024];
  const int i = blockIdx.x * 1024 + threadIdx.x;
  const int v = (i < n) ? counts[i] : 0;
  sm[threadIdx.x] = v;
  __syncthreads();
  for (int off = 1; off < 1024; off <<= 1) {
    int t = sm[threadIdx.x];
    int u = (threadIdx.x >= off) ? sm[threadIdx.x - off] : 0;
    __syncthreads();
    sm[threadIdx.x] = t + u;
    __syncthreads();
  }
  const int inc = sm[threadIdx.x];
  if (i < n) scanned[i] = inc - v;  // exclusive
  if (threadIdx.x == 1023) partials[blockIdx.x] = inc;
}

__global__ __launch_bounds__(1024) void k_scan2(int* __restrict__ partials, int nb) {
  __shared__ int sm[1024];
  const int v = (threadIdx.x < nb) ? partials[threadIdx.x] : 0;
  sm[threadIdx.x] = v;
  __syncthreads();
  for (int off = 1; off < 1024; off <<= 1) {
    int t = sm[threadIdx.x];
    int u = (threadIdx.x >= off) ? sm[threadIdx.x - off] : 0;
    __syncthreads();
    sm[threadIdx.x] = t + u;
    __syncthreads();
  }
  if (threadIdx.x < nb) partials[threadIdx.x] = sm[threadIdx.x] - v;  // exclusive
}

__global__ __launch_bounds__(256) void k_scan3(const int* __restrict__ scanned,
                                               const int* __restrict__ partials,
                                               const int* __restrict__ counts,
                                               int* __restrict__ offsets,
                                               int* __restrict__ cursor,
                                               float* __restrict__ dinv, int n) {
  int i = blockIdx.x * blockDim.x + threadIdx.x;
  const int stride = gridDim.x * blockDim.x;
  for (; i < n; i += stride) {
    const int o = scanned[i] + partials[i >> 10];
    offsets[i] = o;
    cursor[i] = o;
    dinv[i] = rsqrtf((float)counts[i] + 1.0f);  // +1 self-loop
  }
}

__global__ __launch_bounds__(256) void k_fill(const void* __restrict__ eraw, int E,
                                              const int* __restrict__ flag,
                                              int* __restrict__ cursor,
                                              int* __restrict__ elist) {
  const int is64 = flag[0];
  int i = blockIdx.x * blockDim.x + threadIdx.x;
  const int stride = gridDim.x * blockDim.x;
  if (is64) {
    const long long* e = (const long long*)eraw;
    for (; i < E; i += stride) {
      const int s = (int)e[i];
      const int d = (int)e[(long long)E + i];
      elist[atomicAdd(&cursor[d], 1)] = s;
    }
  } else {
    const int* e = (const int*)eraw;
    for (; i < E; i += stride) {
      const int s = e[i];
      const int d = e[E + i];
      elist[atomicAdd(&cursor[d], 1)] = s;
    }
  }
}

// hs = dinv .* (X @ W).  256 thr, 4x4 thread tile.
// X tile XOR-swizzled: LDS float4-slot row*K4+c holds X[row][c ^ (row&7)].
// Staged via global_load_lds with PRE-SWIZZLED global source (linear LDS dest).
// W chunks double-buffered (single-buffered when NKC==1).
template <int F_IN, int F_OUT, int TILE_M, int KC>
__global__ __launch_bounds__(256) void k_transform(const float* __restrict__ X,
                                                   const float* __restrict__ W,
                                                   const float* __restrict__ dinv,
                                                   float* __restrict__ H, int n) {
  constexpr int COLT = F_OUT / 4;
  constexpr int ROWT = 256 / COLT;
  constexpr int TM = TILE_M / ROWT;
  constexpr int NKC = F_IN / KC;
  constexpr int K4 = F_IN / 4;
  constexpr int NWB = (NKC > 1) ? 2 : 1;  // W buffers
  static_assert(TM * ROWT == TILE_M && COLT * 4 == F_OUT, "tiling");
  static_assert((TILE_M * F_IN * 4) % 1024 == 0 && (KC * F_OUT * 4) % 1024 == 0, "segs");
  static_assert(K4 >= 8, "swizzle range");

  __shared__ __align__(16) float Xs[TILE_M * F_IN];
  __shared__ __align__(16) float Ws[NWB][KC * F_OUT];

  const int tid = threadIdx.x;
  const int lane = tid & 63;
  const int wid = tid >> 6;
  const long long base = (long long)blockIdx.x * TILE_M;

  const float4* __restrict__ X4 = (const float4*)X;
  if (base + TILE_M <= n) {  // full tile: async staged, pre-swizzled source
    constexpr int SEGS = TILE_M * F_IN * 4 / 1024;  // 1KB segments
    constexpr int PW = SEGS / 4;
    #pragma unroll
    for (int j = 0; j < PW; ++j) {
      const int seg = wid * PW + j;
      const int slot = seg * 64 + lane;           // linear LDS float4 slot
      const int row = slot / K4;
      const int c = slot % K4;
      const int ksrc = c ^ (row & 7);             // inverse swizzle on source
      gld16(&X4[(base + row) * K4 + ksrc], &Xs[seg * 256]);
    }
  } else {  // tail tile: guarded staging with same swizzled layout
    for (int slot = tid; slot < TILE_M * K4; slot += 256) {
      const int row = slot / K4;
      const int c = slot % K4;
      float4 v = make_float4(0.f, 0.f, 0.f, 0.f);
      if (base + row < n) v = X4[(base + row) * K4 + (c ^ (row & 7))];
      ((float4*)Xs)[slot] = v;
    }
  }

  // stage W chunk 0
  constexpr int WSEG = KC * F_OUT * 4 / 1024;
  constexpr int WPW = WSEG / 4;
  {
    #pragma unroll
    for (int j = 0; j < WPW; ++j) {
      const int seg = wid * WPW + j;
      gld16(W + seg * 256 + lane * 4, &Ws[0][seg * 256]);
    }
  }

  const int ct = tid % COLT;
  const int rt = tid / COLT;
  const int sw = rt & 7;  // row&7 is invariant across r (ROWT multiple of 8)

  float4 acc[TM];
  #pragma unroll
  for (int r = 0; r < TM; ++r) acc[r] = make_float4(0.f, 0.f, 0.f, 0.f);

  const float4* Xs4 = (const float4*)Xs;

  for (int kc = 0; kc < NKC; ++kc) {
    __syncthreads();  // current W chunk + X staged (vmcnt drained at barrier)
    if (NKC > 1 && kc + 1 < NKC) {  // prefetch next W chunk into other buffer
      const float* wb = W + (kc + 1) * KC * F_OUT;
      #pragma unroll
      for (int j = 0; j < WPW; ++j) {
        const int seg = wid * WPW + j;
        gld16(wb + seg * 256 + lane * 4, &Ws[(kc + 1) & (NWB - 1)][seg * 256]);
      }
    }
    const float4* Ws4 = (const float4*)Ws[kc & (NWB - 1)];
    #pragma unroll
    for (int k4 = 0; k4 < KC / 4; ++k4) {
      const int kk = kc * (KC / 4) + k4;
      float4 wv0 = Ws4[(k4 * 4 + 0) * COLT + ct];
      float4 wv1 = Ws4[(k4 * 4 + 1) * COLT + ct];
      float4 wv2 = Ws4[(k4 * 4 + 2) * COLT + ct];
      float4 wv3 = Ws4[(k4 * 4 + 3) * COLT + ct];
      #pragma unroll
      for (int r = 0; r < TM; ++r) {
        const float4 xv = Xs4[(rt + r * ROWT) * K4 + (kk ^ sw)];
        acc[r].x = fmaf(xv.x, wv0.x, acc[r].x);
        acc[r].y = fmaf(xv.x, wv0.y, acc[r].y);
        acc[r].z = fmaf(xv.x, wv0.z, acc[r].z);
        acc[r].w = fmaf(xv.x, wv0.w, acc[r].w);
        acc[r].x = fmaf(xv.y, wv1.x, acc[r].x);
        acc[r].y = fmaf(xv.y, wv1.y, acc[r].y);
        acc[r].z = fmaf(xv.y, wv1.z, acc[r].z);
        acc[r].w = fmaf(xv.y, wv1.w, acc[r].w);
        acc[r].x = fmaf(xv.z, wv2.x, acc[r].x);
        acc[r].y = fmaf(xv.z, wv2.y, acc[r].y);
        acc[r].z = fmaf(xv.z, wv2.z, acc[r].z);
        acc[r].w = fmaf(xv.z, wv2.w, acc[r].w);
        acc[r].x = fmaf(xv.w, wv3.x, acc[r].x);
        acc[r].y = fmaf(xv.w, wv3.y, acc[r].y);
        acc[r].z = fmaf(xv.w, wv3.z, acc[r].z);
        acc[r].w = fmaf(xv.w, wv3.w, acc[r].w);
      }
    }
  }

  #pragma unroll
  for (int r = 0; r < TM; ++r) {
    const long long row = base + rt + r * ROWT;
    if (row < n) {
      const float di = dinv[row];
      float4 v = acc[r];
      v.x *= di; v.y *= di; v.z *= di; v.w *= di;
      *(float4*)&H[row * F_OUT + ct * 4] = v;
    }
  }
}

// out[d][f] = relu?(b[f] + dinv[d]*(hs[d][f] + sum_s hs[s][f]))
// 8-wide predicated gather batches: 8 independent loads in flight per group.
// FUSE_W3: additionally hs3 = dinv .* (relu(out2) @ W3)  (F_OUT=2).
template <int F, bool RELU_OUT, bool FUSE_W3>
__global__ __launch_bounds__(256) void k_aggregate(const float* __restrict__ HS,
                                                   const float* __restrict__ dinv,
                                                   const int* __restrict__ offsets,
                                                   const int* __restrict__ counts,
                                                   const int* __restrict__ elist,
                                                   const float* __restrict__ bias,
                                                   const float* __restrict__ W3,
                                                   float* __restrict__ out, int n) {
  const int f = threadIdx.x % F;
  const int grp = threadIdx.x / F;
  constexpr int GRPS = 256 / F;
  const float bf = bias[f];
  float w30 = 0.f, w31 = 0.f;
  if (FUSE_W3) { w30 = W3[f * 2 + 0]; w31 = W3[f * 2 + 1]; }

  for (long long d = (long long)blockIdx.x * GRPS + grp; d < n;
       d += (long long)gridDim.x * GRPS) {
    const float di = dinv[d];
    float acc = HS[d * F + f];  // self-loop (already dinv[d]-scaled)
    const int start = offsets[d];
    const int cnt = counts[d];
    for (int j = 0; j < cnt; j += 8) {
      int idx[8];
      float v[8];
      #pragma unroll
      for (int t = 0; t < 8; ++t) {
        const int jj = (j + t < cnt) ? (j + t) : j;  // clamp to a valid slot
        idx[t] = elist[start + jj];
      }
      #pragma unroll
      for (int t = 0; t < 8; ++t) v[t] = HS[(long long)idx[t] * F + f];
      #pragma unroll
      for (int t = 0; t < 8; ++t) acc += (j + t < cnt) ? v[t] : 0.f;
    }

    float r = fmaf(di, acc, bf);
    if (RELU_OUT) r = fmaxf(r, 0.f);
    if (!FUSE_W3) {
      out[d * F + f] = r;
    } else {
      float t0 = r * w30, t1 = r * w31;
      #pragma unroll
      for (int m = 1; m < 32; m <<= 1) {
        t0 += __shfl_xor(t0, m, 64);
        t1 += __shfl_xor(t1, m, 64);
      }
      if (f == 0) {
        out[d * 2 + 0] = di * t0;
        out[d * 2 + 1] = di * t1;
      }
    }
  }
}

extern "C" void kernel_launch(void* const* d_in, const int* in_sizes, int n_in,
                              void* d_out, int out_size, void* d_ws, size_t ws_size,
                              hipStream_t stream) {
  const float* x = (const float*)d_in[0];
  const void* eraw = d_in[1];
  const float* W1 = (const float*)d_in[2];
  const float* b1 = (const float*)d_in[3];
  const float* W2 = (const float*)d_in[4];
  const float* b2 = (const float*)d_in[5];
  const float* W3 = (const float*)d_in[6];
  const float* b3 = (const float*)d_in[7];
  float* out = (float*)d_out;

  const int N = in_sizes[0] / 128;  // 100000
  const int E = in_sizes[1] / 2;    // 600000

  char* ws = (char*)d_ws;
  size_t off = 0;
  auto alloc = [&](size_t bytes) -> char* {
    char* p = ws + off;
    off = (off + bytes + 255) & ~(size_t)255;
    return p;
  };
  int*   flag     = (int*)alloc(256);
  int*   counts   = (int*)alloc((size_t)N * 4 + 16);
  int*   scanned  = (int*)alloc((size_t)N * 4);
  int*   partials = (int*)alloc(1024 * 4);
  int*   offsets  = (int*)alloc((size_t)N * 4);
  int*   cursor   = (int*)alloc((size_t)N * 4);
  int*   elist    = (int*)alloc((size_t)E * 4);
  float* dinv     = (float*)alloc((size_t)N * 4);
  float* hbuf     = (float*)alloc((size_t)N * 64 * 4);  // hs1 [N,64]; later hs3 [N,2]
  float* obuf     = (float*)alloc((size_t)N * 64 * 4);  // out1 [N,64]
  float* h2buf    = (float*)alloc((size_t)N * 32 * 4);  // hs2 [N,32]
  (void)ws_size; (void)n_in; (void)out_size;

  // ---- CSR build ----
  k_zero<<<128, 256, 0, stream>>>(counts, (N + 3) / 4);
  k_detect<<<1, 256, 0, stream>>>((const unsigned int*)eraw, flag);
  k_hist<<<FULL_GRID, 256, 0, stream>>>(eraw, E, flag, counts);
  const int NB = (N + 1023) >> 10;
  k_scan1<<<NB, 1024, 0, stream>>>(counts, scanned, partials, N);
  k_scan2<<<1, 1024, 0, stream>>>(partials, NB);
  k_scan3<<<(N + 255) / 256, 256, 0, stream>>>(scanned, partials, counts, offsets,
                                               cursor, dinv, N);
  k_fill<<<FULL_GRID, 256, 0, stream>>>(eraw, E, flag, cursor, elist);

  // ---- layer 1: hs1 = dinv.*(x@W1); out1 = relu(agg(hs1)) ----
  k_transform<128, 64, 64, 16><<<(N + 63) / 64, 256, 0, stream>>>(x, W1, dinv, hbuf, N);
  k_aggregate<64, true, false><<<(N + 3) / 4, 256, 0, stream>>>(
      hbuf, dinv, offsets, counts, elist, b1, nullptr, obuf, N);

  // ---- layer 2: hs2 = dinv.*(out1@W2); agg + ReLU + fused W3 -> hs3 ----
  k_transform<64, 32, 128, 64><<<(N + 127) / 128, 256, 0, stream>>>(obuf, W2, dinv,
                                                                    h2buf, N);
  k_aggregate<32, true, true><<<(N + 7) / 8, 256, 0, stream>>>(
      h2buf, dinv, offsets, counts, elist, b2, W3, hbuf, N);

  // ---- layer 3: agg hs3 + ReLU -> out ----
  k_aggregate<2, true, false><<<(N + 127) / 128, 256, 0, stream>>>(
      hbuf, dinv, offsets, counts, elist, b3, nullptr, out, N);
}

// Round 6
// 197.051 us; speedup vs baseline: 1.7615x; 1.0250x over previous
//
#include <hip/hip_runtime.h>
#include <math.h>

// ---------------------------------------------------------------------------
// GCNEncoder: 3 stacked GCNConv layers (symmetric norm, self-loops) + ReLU.
//   R6: (a) t1 re-tiled to TILE_M=128/TM=8 -> FMA-bound (12 LDS reads : 128
//       FMAs per k4-step); (b) k_hist/k_fill XCD-partitioned (blockIdx&7 ->
//       dst range) so scattered stores/atomics stay in one XCD's L2
//       (k_fill was 39us, WRITE 36.5MB for a 2.4MB elist).
//   Carried: XOR-swizzled X staging via pre-swizzled global_load_lds src,
//   W double-buffer, custom k_zero, low-VGPR 8-wide-batch aggregates,
//   W3 fused into agg2 via shuffle reduce.
// ---------------------------------------------------------------------------

#define FULL_GRID 2048
#define PARTS 8

typedef const __attribute__((address_space(1))) void* gas_ptr;
typedef __attribute__((address_space(3))) void* las_ptr;

__device__ __forceinline__ void gld16(const void* g, void* l) {
  __builtin_amdgcn_global_load_lds((gas_ptr)g, (las_ptr)l, 16, 0, 0);
}

__global__ __launch_bounds__(256) void k_zero(int* __restrict__ p, int n4) {
  int i = blockIdx.x * blockDim.x + threadIdx.x;
  const int stride = gridDim.x * blockDim.x;
  int4* p4 = (int4*)p;
  for (; i < n4; i += stride) p4[i] = make_int4(0, 0, 0, 0);
}

__global__ __launch_bounds__(256) void k_detect(const unsigned int* __restrict__ words,
                                                int* __restrict__ flag) {
  __shared__ int sm[256];
  int cnt = 0;
  #pragma unroll
  for (int j = 0; j < 8; ++j) {
    int idx = (threadIdx.x * 8 + j) * 2 + 1;  // odd words of first 4096 words
    cnt += (words[idx] == 0u) ? 1 : 0;
  }
  sm[threadIdx.x] = cnt;
  __syncthreads();
  for (int off = 128; off > 0; off >>= 1) {
    if (threadIdx.x < off) sm[threadIdx.x] += sm[threadIdx.x + off];
    __syncthreads();
  }
  if (threadIdx.x == 0) flag[0] = (sm[0] > 1024) ? 1 : 0;
}

// XCD-partitioned histogram: partition p = blockIdx&7 handles dst range
// [lo,hi) so atomics on counts stay in one XCD's L2.
__global__ __launch_bounds__(256) void k_hist(const void* __restrict__ eraw, int E,
                                              int N, const int* __restrict__ flag,
                                              int* __restrict__ counts) {
  const int is64 = flag[0];
  const int part = blockIdx.x & (PARTS - 1);
  const int lo = (int)((long long)N * part / PARTS);
  const int hi = (int)((long long)N * (part + 1) / PARTS);
  int i = (blockIdx.x >> 3) * blockDim.x + threadIdx.x;
  const int stride = (gridDim.x >> 3) * blockDim.x;
  if (is64) {
    const long long* e = (const long long*)eraw;
    for (; i < E; i += stride) {
      const int d = (int)e[(long long)E + i];
      if (d >= lo && d < hi) atomicAdd(&counts[d], 1);
    }
  } else {
    const int* e = (const int*)eraw;
    for (; i < E; i += stride) {
      const int d = e[E + i];
      if (d >= lo && d < hi) atomicAdd(&counts[d], 1);
    }
  }
}

__global__ __launch_bounds__(1024) void k_scan1(const int* __restrict__ counts,
                                                int* __restrict__ scanned,
                                                int* __restrict__ partials, int n) {
  __shared__ int sm[1024];
  const int i = blockIdx.x * 1024 + threadIdx.x;
  const int v = (i < n) ? counts[i] : 0;
  sm[threadIdx.x] = v;
  __syncthreads();
  for (int off = 1; off < 1024; off <<= 1) {
    int t = sm[threadIdx.x];
    int u = (threadIdx.x >= off) ? sm[threadIdx.x - off] : 0;
    __syncthreads();
    sm[threadIdx.x] = t + u;
    __syncthreads();
  }
  const int inc = sm[threadIdx.x];
  if (i < n) scanned[i] = inc - v;  // exclusive
  if (threadIdx.x == 1023) partials[blockIdx.x] = inc;
}

__global__ __launch_bounds__(1024) void k_scan2(int* __restrict__ partials, int nb) {
  __shared__ int sm[1024];
  const int v = (threadIdx.x < nb) ? partials[threadIdx.x] : 0;
  sm[threadIdx.x] = v;
  __syncthreads();
  for (int off = 1; off < 1024; off <<= 1) {
    int t = sm[threadIdx.x];
    int u = (threadIdx.x >= off) ? sm[threadIdx.x - off] : 0;
    __syncthreads();
    sm[threadIdx.x] = t + u;
    __syncthreads();
  }
  if (threadIdx.x < nb) partials[threadIdx.x] = sm[threadIdx.x] - v;  // exclusive
}

__global__ __launch_bounds__(256) void k_scan3(const int* __restrict__ scanned,
                                               const int* __restrict__ partials,
                                               const int* __restrict__ counts,
                                               int* __restrict__ offsets,
                                               int* __restrict__ cursor,
                                               float* __restrict__ dinv, int n) {
  int i = blockIdx.x * blockDim.x + threadIdx.x;
  const int stride = gridDim.x * blockDim.x;
  for (; i < n; i += stride) {
    const int o = scanned[i] + partials[i >> 10];
    offsets[i] = o;
    cursor[i] = o;
    dinv[i] = rsqrtf((float)counts[i] + 1.0f);  // +1 self-loop
  }
}

// XCD-partitioned fill: stores to elist confined to this partition's slice.
__global__ __launch_bounds__(256) void k_fill(const void* __restrict__ eraw, int E,
                                              int N, const int* __restrict__ flag,
                                              int* __restrict__ cursor,
                                              int* __restrict__ elist) {
  const int is64 = flag[0];
  const int part = blockIdx.x & (PARTS - 1);
  const int lo = (int)((long long)N * part / PARTS);
  const int hi = (int)((long long)N * (part + 1) / PARTS);
  int i = (blockIdx.x >> 3) * blockDim.x + threadIdx.x;
  const int stride = (gridDim.x >> 3) * blockDim.x;
  if (is64) {
    const long long* e = (const long long*)eraw;
    for (; i < E; i += stride) {
      const int d = (int)e[(long long)E + i];
      if (d >= lo && d < hi) {
        const int s = (int)e[i];
        elist[atomicAdd(&cursor[d], 1)] = s;
      }
    }
  } else {
    const int* e = (const int*)eraw;
    for (; i < E; i += stride) {
      const int d = e[E + i];
      if (d >= lo && d < hi) {
        const int s = e[i];
        elist[atomicAdd(&cursor[d], 1)] = s;
      }
    }
  }
}

// hs = dinv .* (X @ W).  THREADS thr, TM x 4 thread tile.
// X tile XOR-swizzled: LDS float4-slot row*K4+c holds X[row][4*(c^(row&7))..].
// Staged via global_load_lds with PRE-SWIZZLED global source (linear LDS dest).
// W chunks double-buffered (single-buffered when NKC==1).
template <int F_IN, int F_OUT, int TILE_M, int KC, int THREADS>
__global__ __launch_bounds__(THREADS) void k_transform(const float* __restrict__ X,
                                                       const float* __restrict__ W,
                                                       const float* __restrict__ dinv,
                                                       float* __restrict__ H, int n) {
  constexpr int COLT = F_OUT / 4;
  constexpr int ROWT = THREADS / COLT;
  constexpr int TM = TILE_M / ROWT;
  constexpr int NKC = F_IN / KC;
  constexpr int K4 = F_IN / 4;
  constexpr int NWB = (NKC > 1) ? 2 : 1;  // W buffers
  static_assert(TM * ROWT == TILE_M && COLT * 4 == F_OUT, "tiling");
  static_assert((TILE_M * F_IN * 4) % 1024 == 0 && (KC * F_OUT * 4) % 1024 == 0, "segs");
  static_assert(K4 >= 8, "swizzle range");
  static_assert(ROWT % 8 == 0, "swizzle invariance across r");

  __shared__ __align__(16) float Xs[TILE_M * F_IN];
  __shared__ __align__(16) float Ws[NWB][KC * F_OUT];

  const int tid = threadIdx.x;
  const int lane = tid & 63;
  const int wid = tid >> 6;
  constexpr int NWAVES = THREADS / 64;
  const long long base = (long long)blockIdx.x * TILE_M;

  const float4* __restrict__ X4 = (const float4*)X;
  if (base + TILE_M <= n) {  // full tile: async staged, pre-swizzled source
    constexpr int SEGS = TILE_M * F_IN * 4 / 1024;  // 1KB segments
    constexpr int PW = SEGS / NWAVES;
    #pragma unroll
    for (int j = 0; j < PW; ++j) {
      const int seg = wid * PW + j;
      const int slot = seg * 64 + lane;           // linear LDS float4 slot
      const int row = slot / K4;
      const int c = slot % K4;
      const int ksrc = c ^ (row & 7);             // inverse swizzle on source
      gld16(&X4[(base + row) * K4 + ksrc], &Xs[seg * 256]);
    }
  } else {  // tail tile: guarded staging with same swizzled layout
    for (int slot = tid; slot < TILE_M * K4; slot += THREADS) {
      const int row = slot / K4;
      const int c = slot % K4;
      float4 v = make_float4(0.f, 0.f, 0.f, 0.f);
      if (base + row < n) v = X4[(base + row) * K4 + (c ^ (row & 7))];
      ((float4*)Xs)[slot] = v;
    }
  }

  // stage W chunk 0
  constexpr int WSEG = KC * F_OUT * 4 / 1024;
  constexpr int WPW = WSEG / NWAVES;
  static_assert(WPW >= 1, "W seg per wave");
  {
    #pragma unroll
    for (int j = 0; j < WPW; ++j) {
      const int seg = wid * WPW + j;
      gld16(W + seg * 256 + lane * 4, &Ws[0][seg * 256]);
    }
  }

  const int ct = tid % COLT;
  const int rt = tid / COLT;
  const int sw = rt & 7;  // row&7 invariant across r (ROWT multiple of 8)

  float4 acc[TM];
  #pragma unroll
  for (int r = 0; r < TM; ++r) acc[r] = make_float4(0.f, 0.f, 0.f, 0.f);

  const float4* Xs4 = (const float4*)Xs;

  for (int kc = 0; kc < NKC; ++kc) {
    __syncthreads();  // current W chunk + X staged (vmcnt drained at barrier)
    if (NKC > 1 && kc + 1 < NKC) {  // prefetch next W chunk into other buffer
      const float* wb = W + (kc + 1) * KC * F_OUT;
      #pragma unroll
      for (int j = 0; j < WPW; ++j) {
        const int seg = wid * WPW + j;
        gld16(wb + seg * 256 + lane * 4, &Ws[(kc + 1) & (NWB - 1)][seg * 256]);
      }
    }
    const float4* Ws4 = (const float4*)Ws[kc & (NWB - 1)];
    #pragma unroll
    for (int k4 = 0; k4 < KC / 4; ++k4) {
      const int kk = kc * (KC / 4) + k4;
      float4 wv0 = Ws4[(k4 * 4 + 0) * COLT + ct];
      float4 wv1 = Ws4[(k4 * 4 + 1) * COLT + ct];
      float4 wv2 = Ws4[(k4 * 4 + 2) * COLT + ct];
      float4 wv3 = Ws4[(k4 * 4 + 3) * COLT + ct];
      #pragma unroll
      for (int r = 0; r < TM; ++r) {
        const float4 xv = Xs4[(rt + r * ROWT) * K4 + (kk ^ sw)];
        acc[r].x = fmaf(xv.x, wv0.x, acc[r].x);
        acc[r].y = fmaf(xv.x, wv0.y, acc[r].y);
        acc[r].z = fmaf(xv.x, wv0.z, acc[r].z);
        acc[r].w = fmaf(xv.x, wv0.w, acc[r].w);
        acc[r].x = fmaf(xv.y, wv1.x, acc[r].x);
        acc[r].y = fmaf(xv.y, wv1.y, acc[r].y);
        acc[r].z = fmaf(xv.y, wv1.z, acc[r].z);
        acc[r].w = fmaf(xv.y, wv1.w, acc[r].w);
        acc[r].x = fmaf(xv.z, wv2.x, acc[r].x);
        acc[r].y = fmaf(xv.z, wv2.y, acc[r].y);
        acc[r].z = fmaf(xv.z, wv2.z, acc[r].z);
        acc[r].w = fmaf(xv.z, wv2.w, acc[r].w);
        acc[r].x = fmaf(xv.w, wv3.x, acc[r].x);
        acc[r].y = fmaf(xv.w, wv3.y, acc[r].y);
        acc[r].z = fmaf(xv.w, wv3.z, acc[r].z);
        acc[r].w = fmaf(xv.w, wv3.w, acc[r].w);
      }
    }
  }

  #pragma unroll
  for (int r = 0; r < TM; ++r) {
    const long long row = base + rt + r * ROWT;
    if (row < n) {
      const float di = dinv[row];
      float4 v = acc[r];
      v.x *= di; v.y *= di; v.z *= di; v.w *= di;
      *(float4*)&H[row * F_OUT + ct * 4] = v;
    }
  }
}

// out[d][f] = relu?(b[f] + dinv[d]*(hs[d][f] + sum_s hs[s][f]))
// 8-wide predicated gather batches: 8 independent loads in flight per group.
// FUSE_W3: additionally hs3 = dinv .* (relu(out2) @ W3)  (F_OUT=2).
template <int F, bool RELU_OUT, bool FUSE_W3>
__global__ __launch_bounds__(256) void k_aggregate(const float* __restrict__ HS,
                                                   const float* __restrict__ dinv,
                                                   const int* __restrict__ offsets,
                                                   const int* __restrict__ counts,
                                                   const int* __restrict__ elist,
                                                   const float* __restrict__ bias,
                                                   const float* __restrict__ W3,
                                                   float* __restrict__ out, int n) {
  const int f = threadIdx.x % F;
  const int grp = threadIdx.x / F;
  constexpr int GRPS = 256 / F;
  const float bf = bias[f];
  float w30 = 0.f, w31 = 0.f;
  if (FUSE_W3) { w30 = W3[f * 2 + 0]; w31 = W3[f * 2 + 1]; }

  for (long long d = (long long)blockIdx.x * GRPS + grp; d < n;
       d += (long long)gridDim.x * GRPS) {
    const float di = dinv[d];
    float acc = HS[d * F + f];  // self-loop (already dinv[d]-scaled)
    const int start = offsets[d];
    const int cnt = counts[d];
    for (int j = 0; j < cnt; j += 8) {
      int idx[8];
      float v[8];
      #pragma unroll
      for (int t = 0; t < 8; ++t) {
        const int jj = (j + t < cnt) ? (j + t) : j;  // clamp to a valid slot
        idx[t] = elist[start + jj];
      }
      #pragma unroll
      for (int t = 0; t < 8; ++t) v[t] = HS[(long long)idx[t] * F + f];
      #pragma unroll
      for (int t = 0; t < 8; ++t) acc += (j + t < cnt) ? v[t] : 0.f;
    }

    float r = fmaf(di, acc, bf);
    if (RELU_OUT) r = fmaxf(r, 0.f);
    if (!FUSE_W3) {
      out[d * F + f] = r;
    } else {
      float t0 = r * w30, t1 = r * w31;
      #pragma unroll
      for (int m = 1; m < 32; m <<= 1) {
        t0 += __shfl_xor(t0, m, 64);
        t1 += __shfl_xor(t1, m, 64);
      }
      if (f == 0) {
        out[d * 2 + 0] = di * t0;
        out[d * 2 + 1] = di * t1;
      }
    }
  }
}

extern "C" void kernel_launch(void* const* d_in, const int* in_sizes, int n_in,
                              void* d_out, int out_size, void* d_ws, size_t ws_size,
                              hipStream_t stream) {
  const float* x = (const float*)d_in[0];
  const void* eraw = d_in[1];
  const float* W1 = (const float*)d_in[2];
  const float* b1 = (const float*)d_in[3];
  const float* W2 = (const float*)d_in[4];
  const float* b2 = (const float*)d_in[5];
  const float* W3 = (const float*)d_in[6];
  const float* b3 = (const float*)d_in[7];
  float* out = (float*)d_out;

  const int N = in_sizes[0] / 128;  // 100000
  const int E = in_sizes[1] / 2;    // 600000

  char* ws = (char*)d_ws;
  size_t off = 0;
  auto alloc = [&](size_t bytes) -> char* {
    char* p = ws + off;
    off = (off + bytes + 255) & ~(size_t)255;
    return p;
  };
  int*   flag     = (int*)alloc(256);
  int*   counts   = (int*)alloc((size_t)N * 4 + 16);
  int*   scanned  = (int*)alloc((size_t)N * 4);
  int*   partials = (int*)alloc(1024 * 4);
  int*   offsets  = (int*)alloc((size_t)N * 4);
  int*   cursor   = (int*)alloc((size_t)N * 4);
  int*   elist    = (int*)alloc((size_t)E * 4);
  float* dinv     = (float*)alloc((size_t)N * 4);
  float* hbuf     = (float*)alloc((size_t)N * 64 * 4);  // hs1 [N,64]; later hs3 [N,2]
  float* obuf     = (float*)alloc((size_t)N * 64 * 4);  // out1 [N,64]
  float* h2buf    = (float*)alloc((size_t)N * 32 * 4);  // hs2 [N,32]
  (void)ws_size; (void)n_in; (void)out_size;

  // ---- CSR build ----
  k_zero<<<128, 256, 0, stream>>>(counts, (N + 3) / 4);
  k_detect<<<1, 256, 0, stream>>>((const unsigned int*)eraw, flag);
  k_hist<<<FULL_GRID, 256, 0, stream>>>(eraw, E, N, flag, counts);
  const int NB = (N + 1023) >> 10;
  k_scan1<<<NB, 1024, 0, stream>>>(counts, scanned, partials, N);
  k_scan2<<<1, 1024, 0, stream>>>(partials, NB);
  k_scan3<<<(N + 255) / 256, 256, 0, stream>>>(scanned, partials, counts, offsets,
                                               cursor, dinv, N);
  k_fill<<<FULL_GRID, 256, 0, stream>>>(eraw, E, N, flag, cursor, elist);

  // ---- layer 1: hs1 = dinv.*(x@W1); out1 = relu(agg(hs1)) ----
  k_transform<128, 64, 128, 16, 256><<<(N + 127) / 128, 256, 0, stream>>>(
      x, W1, dinv, hbuf, N);
  k_aggregate<64, true, false><<<(N + 3) / 4, 256, 0, stream>>>(
      hbuf, dinv, offsets, counts, elist, b1, nullptr, obuf, N);

  // ---- layer 2: hs2 = dinv.*(out1@W2); agg + ReLU + fused W3 -> hs3 ----
  k_transform<64, 32, 128, 64, 256><<<(N + 127) / 128, 256, 0, stream>>>(
      obuf, W2, dinv, h2buf, N);
  k_aggregate<32, true, true><<<(N + 7) / 8, 256, 0, stream>>>(
      h2buf, dinv, offsets, counts, elist, b2, W3, hbuf, N);

  // ---- layer 3: agg hs3 + ReLU -> out ----
  k_aggregate<2, true, false><<<(N + 127) / 128, 256, 0, stream>>>(
      hbuf, dinv, offsets, counts, elist, b3, nullptr, out, N);
}

// Round 7
// 190.732 us; speedup vs baseline: 1.8198x; 1.0331x over previous
//
#include <hip/hip_runtime.h>
#include <math.h>

// ---------------------------------------------------------------------------
// GCNEncoder: 3 stacked GCNConv layers (symmetric norm, self-loops) + ReLU.
//   R7: transforms rebuilt as PERSISTENT 2-phase pipelined GEMMs:
//       grid-stride over M-tiles, X tile double-buffered, stage(next) issued
//       before compute(cur) so global_load_lds flies under the FMA phase
//       (R6 showed stage+compute serialized: VALUBusy 28%, occ 14.5%).
//       W staged once per kernel. XOR-swizzle carried (bank conflicts = 0).
//   Carried: XCD-partitioned hist/fill, custom k_zero, low-VGPR 8-wide-batch
//   aggregates, W3 fused into agg2 via shuffle reduce.
// ---------------------------------------------------------------------------

#define FULL_GRID 2048
#define PARTS 8

typedef const __attribute__((address_space(1))) void* gas_ptr;
typedef __attribute__((address_space(3))) void* las_ptr;

__device__ __forceinline__ void gld16(const void* g, void* l) {
  __builtin_amdgcn_global_load_lds((gas_ptr)g, (las_ptr)l, 16, 0, 0);
}

__global__ __launch_bounds__(256) void k_zero(int* __restrict__ p, int n4) {
  int i = blockIdx.x * blockDim.x + threadIdx.x;
  const int stride = gridDim.x * blockDim.x;
  int4* p4 = (int4*)p;
  for (; i < n4; i += stride) p4[i] = make_int4(0, 0, 0, 0);
}

__global__ __launch_bounds__(256) void k_detect(const unsigned int* __restrict__ words,
                                                int* __restrict__ flag) {
  __shared__ int sm[256];
  int cnt = 0;
  #pragma unroll
  for (int j = 0; j < 8; ++j) {
    int idx = (threadIdx.x * 8 + j) * 2 + 1;  // odd words of first 4096 words
    cnt += (words[idx] == 0u) ? 1 : 0;
  }
  sm[threadIdx.x] = cnt;
  __syncthreads();
  for (int off = 128; off > 0; off >>= 1) {
    if (threadIdx.x < off) sm[threadIdx.x] += sm[threadIdx.x + off];
    __syncthreads();
  }
  if (threadIdx.x == 0) flag[0] = (sm[0] > 1024) ? 1 : 0;
}

// XCD-partitioned histogram: partition p = blockIdx&7 handles dst range
// [lo,hi) so atomics on counts stay in one XCD's L2.
__global__ __launch_bounds__(256) void k_hist(const void* __restrict__ eraw, int E,
                                              int N, const int* __restrict__ flag,
                                              int* __restrict__ counts) {
  const int is64 = flag[0];
  const int part = blockIdx.x & (PARTS - 1);
  const int lo = (int)((long long)N * part / PARTS);
  const int hi = (int)((long long)N * (part + 1) / PARTS);
  int i = (blockIdx.x >> 3) * blockDim.x + threadIdx.x;
  const int stride = (gridDim.x >> 3) * blockDim.x;
  if (is64) {
    const long long* e = (const long long*)eraw;
    for (; i < E; i += stride) {
      const int d = (int)e[(long long)E + i];
      if (d >= lo && d < hi) atomicAdd(&counts[d], 1);
    }
  } else {
    const int* e = (const int*)eraw;
    for (; i < E; i += stride) {
      const int d = e[E + i];
      if (d >= lo && d < hi) atomicAdd(&counts[d], 1);
    }
  }
}

__global__ __launch_bounds__(1024) void k_scan1(const int* __restrict__ counts,
                                                int* __restrict__ scanned,
                                                int* __restrict__ partials, int n) {
  __shared__ int sm[1024];
  const int i = blockIdx.x * 1024 + threadIdx.x;
  const int v = (i < n) ? counts[i] : 0;
  sm[threadIdx.x] = v;
  __syncthreads();
  for (int off = 1; off < 1024; off <<= 1) {
    int t = sm[threadIdx.x];
    int u = (threadIdx.x >= off) ? sm[threadIdx.x - off] : 0;
    __syncthreads();
    sm[threadIdx.x] = t + u;
    __syncthreads();
  }
  const int inc = sm[threadIdx.x];
  if (i < n) scanned[i] = inc - v;  // exclusive
  if (threadIdx.x == 1023) partials[blockIdx.x] = inc;
}

__global__ __launch_bounds__(1024) void k_scan2(int* __restrict__ partials, int nb) {
  __shared__ int sm[1024];
  const int v = (threadIdx.x < nb) ? partials[threadIdx.x] : 0;
  sm[threadIdx.x] = v;
  __syncthreads();
  for (int off = 1; off < 1024; off <<= 1) {
    int t = sm[threadIdx.x];
    int u = (threadIdx.x >= off) ? sm[threadIdx.x - off] : 0;
    __syncthreads();
    sm[threadIdx.x] = t + u;
    __syncthreads();
  }
  if (threadIdx.x < nb) partials[threadIdx.x] = sm[threadIdx.x] - v;  // exclusive
}

__global__ __launch_bounds__(256) void k_scan3(const int* __restrict__ scanned,
                                               const int* __restrict__ partials,
                                               const int* __restrict__ counts,
                                               int* __restrict__ offsets,
                                               int* __restrict__ cursor,
                                               float* __restrict__ dinv, int n) {
  int i = blockIdx.x * blockDim.x + threadIdx.x;
  const int stride = gridDim.x * blockDim.x;
  for (; i < n; i += stride) {
    const int o = scanned[i] + partials[i >> 10];
    offsets[i] = o;
    cursor[i] = o;
    dinv[i] = rsqrtf((float)counts[i] + 1.0f);  // +1 self-loop
  }
}

// XCD-partitioned fill: stores to elist confined to this partition's slice.
__global__ __launch_bounds__(256) void k_fill(const void* __restrict__ eraw, int E,
                                              int N, const int* __restrict__ flag,
                                              int* __restrict__ cursor,
                                              int* __restrict__ elist) {
  const int is64 = flag[0];
  const int part = blockIdx.x & (PARTS - 1);
  const int lo = (int)((long long)N * part / PARTS);
  const int hi = (int)((long long)N * (part + 1) / PARTS);
  int i = (blockIdx.x >> 3) * blockDim.x + threadIdx.x;
  const int stride = (gridDim.x >> 3) * blockDim.x;
  if (is64) {
    const long long* e = (const long long*)eraw;
    for (; i < E; i += stride) {
      const int d = (int)e[(long long)E + i];
      if (d >= lo && d < hi) {
        const int s = (int)e[i];
        elist[atomicAdd(&cursor[d], 1)] = s;
      }
    }
  } else {
    const int* e = (const int*)eraw;
    for (; i < E; i += stride) {
      const int d = e[E + i];
      if (d >= lo && d < hi) {
        const int s = e[i];
        elist[atomicAdd(&cursor[d], 1)] = s;
      }
    }
  }
}

// hs = dinv .* (X @ W). Persistent blocks, double-buffered X tile, 2-phase
// pipeline: [barrier] -> issue stage(next) -> compute(cur) -> swap.
// X tile XOR-swizzled (pre-swizzled global_load_lds source, swizzled read).
// W staged whole, once.
template <int F_IN, int F_OUT, int TILE_M, int THREADS>
__global__ __launch_bounds__(THREADS) void k_transform(const float* __restrict__ X,
                                                       const float* __restrict__ W,
                                                       const float* __restrict__ dinv,
                                                       float* __restrict__ H, int n,
                                                       int ntiles) {
  constexpr int COLT = F_OUT / 4;
  constexpr int ROWT = THREADS / COLT;
  constexpr int TM = TILE_M / ROWT;
  constexpr int K4 = F_IN / 4;
  constexpr int NWAVES = THREADS / 64;
  constexpr int XSEG = TILE_M * F_IN * 4 / 1024;  // 1KB segments
  constexpr int XPW = XSEG / NWAVES;
  constexpr int WSEG = F_IN * F_OUT * 4 / 1024;
  constexpr int WPW = (WSEG + NWAVES - 1) / NWAVES;
  static_assert(TM * ROWT == TILE_M && COLT * 4 == F_OUT, "tiling");
  static_assert(XPW * NWAVES == XSEG, "X segs per wave");
  static_assert(K4 >= 8, "swizzle range");
  static_assert(ROWT % 8 == 0, "swizzle invariance across r");

  __shared__ __align__(16) float Xs[2][TILE_M * F_IN];
  __shared__ __align__(16) float Ws[F_IN * F_OUT];

  const int tid = threadIdx.x;
  const int lane = tid & 63;
  const int wid = tid >> 6;
  const float4* __restrict__ X4 = (const float4*)X;

  // stage whole W once
  #pragma unroll
  for (int j = 0; j < WPW; ++j) {
    const int seg = wid * WPW + j;
    if (seg < WSEG) gld16(W + seg * 256 + lane * 4, &Ws[seg * 256]);
  }

  auto stage = [&](int buf, int tile) {
    const long long base = (long long)tile * TILE_M;
    if (base + TILE_M <= n) {  // full tile: async staged, pre-swizzled source
      #pragma unroll
      for (int j = 0; j < XPW; ++j) {
        const int seg = wid * XPW + j;
        const int slot = seg * 64 + lane;  // linear LDS float4 slot
        const int row = slot / K4;
        const int c = slot % K4;
        gld16(&X4[(base + row) * K4 + (c ^ (row & 7))], &Xs[buf][seg * 256]);
      }
    } else {  // tail tile: guarded LDS writes, same swizzled layout
      for (int slot = tid; slot < TILE_M * K4; slot += THREADS) {
        const int row = slot / K4;
        const int c = slot % K4;
        float4 v = make_float4(0.f, 0.f, 0.f, 0.f);
        if (base + row < n) v = X4[(base + row) * K4 + (c ^ (row & 7))];
        ((float4*)Xs[buf])[slot] = v;
      }
    }
  };

  const int ct = tid % COLT;
  const int rt = tid / COLT;
  const int sw = rt & 7;  // row&7 invariant across r (ROWT multiple of 8)
  const float4* Ws4 = (const float4*)Ws;

  int tile = blockIdx.x;
  if (tile < ntiles) stage(0, tile);
  int buf = 0;

  for (; tile < ntiles; tile += gridDim.x) {
    __syncthreads();  // cur buffer staged (syncthreads drains vmcnt/lgkm)
    const int nxt = tile + gridDim.x;
    if (nxt < ntiles) stage(buf ^ 1, nxt);  // issue loads; land during compute

    const long long base = (long long)tile * TILE_M;
    float4 acc[TM];
    #pragma unroll
    for (int r = 0; r < TM; ++r) acc[r] = make_float4(0.f, 0.f, 0.f, 0.f);
    const float4* Xs4 = (const float4*)Xs[buf];

    #pragma unroll 4
    for (int k4 = 0; k4 < K4; ++k4) {
      const float4 wv0 = Ws4[(k4 * 4 + 0) * COLT + ct];
      const float4 wv1 = Ws4[(k4 * 4 + 1) * COLT + ct];
      const float4 wv2 = Ws4[(k4 * 4 + 2) * COLT + ct];
      const float4 wv3 = Ws4[(k4 * 4 + 3) * COLT + ct];
      #pragma unroll
      for (int r = 0; r < TM; ++r) {
        const float4 xv = Xs4[(rt + r * ROWT) * K4 + (k4 ^ sw)];
        acc[r].x = fmaf(xv.x, wv0.x, acc[r].x);
        acc[r].y = fmaf(xv.x, wv0.y, acc[r].y);
        acc[r].z = fmaf(xv.x, wv0.z, acc[r].z);
        acc[r].w = fmaf(xv.x, wv0.w, acc[r].w);
        acc[r].x = fmaf(xv.y, wv1.x, acc[r].x);
        acc[r].y = fmaf(xv.y, wv1.y, acc[r].y);
        acc[r].z = fmaf(xv.y, wv1.z, acc[r].z);
        acc[r].w = fmaf(xv.y, wv1.w, acc[r].w);
        acc[r].x = fmaf(xv.z, wv2.x, acc[r].x);
        acc[r].y = fmaf(xv.z, wv2.y, acc[r].y);
        acc[r].z = fmaf(xv.z, wv2.z, acc[r].z);
        acc[r].w = fmaf(xv.z, wv2.w, acc[r].w);
        acc[r].x = fmaf(xv.w, wv3.x, acc[r].x);
        acc[r].y = fmaf(xv.w, wv3.y, acc[r].y);
        acc[r].z = fmaf(xv.w, wv3.z, acc[r].z);
        acc[r].w = fmaf(xv.w, wv3.w, acc[r].w);
      }
    }

    #pragma unroll
    for (int r = 0; r < TM; ++r) {
      const long long row = base + rt + r * ROWT;
      if (row < n) {
        const float di = dinv[row];
        float4 v = acc[r];
        v.x *= di; v.y *= di; v.z *= di; v.w *= di;
        *(float4*)&H[row * F_OUT + ct * 4] = v;
      }
    }
    __syncthreads();  // all waves done reading buf before it is re-staged
    buf ^= 1;
  }
}

// out[d][f] = relu?(b[f] + dinv[d]*(hs[d][f] + sum_s hs[s][f]))
// 8-wide predicated gather batches: 8 independent loads in flight per group.
// FUSE_W3: additionally hs3 = dinv .* (relu(out2) @ W3)  (F_OUT=2).
template <int F, bool RELU_OUT, bool FUSE_W3>
__global__ __launch_bounds__(256) void k_aggregate(const float* __restrict__ HS,
                                                   const float* __restrict__ dinv,
                                                   const int* __restrict__ offsets,
                                                   const int* __restrict__ counts,
                                                   const int* __restrict__ elist,
                                                   const float* __restrict__ bias,
                                                   const float* __restrict__ W3,
                                                   float* __restrict__ out, int n) {
  const int f = threadIdx.x % F;
  const int grp = threadIdx.x / F;
  constexpr int GRPS = 256 / F;
  const float bf = bias[f];
  float w30 = 0.f, w31 = 0.f;
  if (FUSE_W3) { w30 = W3[f * 2 + 0]; w31 = W3[f * 2 + 1]; }

  for (long long d = (long long)blockIdx.x * GRPS + grp; d < n;
       d += (long long)gridDim.x * GRPS) {
    const float di = dinv[d];
    float acc = HS[d * F + f];  // self-loop (already dinv[d]-scaled)
    const int start = offsets[d];
    const int cnt = counts[d];
    for (int j = 0; j < cnt; j += 8) {
      int idx[8];
      float v[8];
      #pragma unroll
      for (int t = 0; t < 8; ++t) {
        const int jj = (j + t < cnt) ? (j + t) : j;  // clamp to a valid slot
        idx[t] = elist[start + jj];
      }
      #pragma unroll
      for (int t = 0; t < 8; ++t) v[t] = HS[(long long)idx[t] * F + f];
      #pragma unroll
      for (int t = 0; t < 8; ++t) acc += (j + t < cnt) ? v[t] : 0.f;
    }

    float r = fmaf(di, acc, bf);
    if (RELU_OUT) r = fmaxf(r, 0.f);
    if (!FUSE_W3) {
      out[d * F + f] = r;
    } else {
      float t0 = r * w30, t1 = r * w31;
      #pragma unroll
      for (int m = 1; m < 32; m <<= 1) {
        t0 += __shfl_xor(t0, m, 64);
        t1 += __shfl_xor(t1, m, 64);
      }
      if (f == 0) {
        out[d * 2 + 0] = di * t0;
        out[d * 2 + 1] = di * t1;
      }
    }
  }
}

extern "C" void kernel_launch(void* const* d_in, const int* in_sizes, int n_in,
                              void* d_out, int out_size, void* d_ws, size_t ws_size,
                              hipStream_t stream) {
  const float* x = (const float*)d_in[0];
  const void* eraw = d_in[1];
  const float* W1 = (const float*)d_in[2];
  const float* b1 = (const float*)d_in[3];
  const float* W2 = (const float*)d_in[4];
  const float* b2 = (const float*)d_in[5];
  const float* W3 = (const float*)d_in[6];
  const float* b3 = (const float*)d_in[7];
  float* out = (float*)d_out;

  const int N = in_sizes[0] / 128;  // 100000
  const int E = in_sizes[1] / 2;    // 600000

  char* ws = (char*)d_ws;
  size_t off = 0;
  auto alloc = [&](size_t bytes) -> char* {
    char* p = ws + off;
    off = (off + bytes + 255) & ~(size_t)255;
    return p;
  };
  int*   flag     = (int*)alloc(256);
  int*   counts   = (int*)alloc((size_t)N * 4 + 16);
  int*   scanned  = (int*)alloc((size_t)N * 4);
  int*   partials = (int*)alloc(1024 * 4);
  int*   offsets  = (int*)alloc((size_t)N * 4);
  int*   cursor   = (int*)alloc((size_t)N * 4);
  int*   elist    = (int*)alloc((size_t)E * 4);
  float* dinv     = (float*)alloc((size_t)N * 4);
  float* hbuf     = (float*)alloc((size_t)N * 64 * 4);  // hs1 [N,64]; later hs3 [N,2]
  float* obuf     = (float*)alloc((size_t)N * 64 * 4);  // out1 [N,64]
  float* h2buf    = (float*)alloc((size_t)N * 32 * 4);  // hs2 [N,32]
  (void)ws_size; (void)n_in; (void)out_size;

  // ---- CSR build ----
  k_zero<<<128, 256, 0, stream>>>(counts, (N + 3) / 4);
  k_detect<<<1, 256, 0, stream>>>((const unsigned int*)eraw, flag);
  k_hist<<<FULL_GRID, 256, 0, stream>>>(eraw, E, N, flag, counts);
  const int NB = (N + 1023) >> 10;
  k_scan1<<<NB, 1024, 0, stream>>>(counts, scanned, partials, N);
  k_scan2<<<1, 1024, 0, stream>>>(partials, NB);
  k_scan3<<<(N + 255) / 256, 256, 0, stream>>>(scanned, partials, counts, offsets,
                                               cursor, dinv, N);
  k_fill<<<FULL_GRID, 256, 0, stream>>>(eraw, E, N, flag, cursor, elist);

  // ---- layer 1: hs1 = dinv.*(x@W1); out1 = relu(agg(hs1)) ----
  {
    const int ntiles = (N + 95) / 96;
    k_transform<128, 64, 96, 512><<<256, 512, 0, stream>>>(x, W1, dinv, hbuf, N,
                                                           ntiles);
  }
  k_aggregate<64, true, false><<<(N + 3) / 4, 256, 0, stream>>>(
      hbuf, dinv, offsets, counts, elist, b1, nullptr, obuf, N);

  // ---- layer 2: hs2 = dinv.*(out1@W2); agg + ReLU + fused W3 -> hs3 ----
  {
    const int ntiles = (N + 127) / 128;
    k_transform<64, 32, 128, 512><<<512, 512, 0, stream>>>(obuf, W2, dinv, h2buf, N,
                                                           ntiles);
  }
  k_aggregate<32, true, true><<<(N + 7) / 8, 256, 0, stream>>>(
      h2buf, dinv, offsets, counts, elist, b2, W3, hbuf, N);

  // ---- layer 3: agg hs3 + ReLU -> out ----
  k_aggregate<2, true, false><<<(N + 127) / 128, 256, 0, stream>>>(
      hbuf, dinv, offsets, counts, elist, b3, nullptr, out, N);
}